// Round 1
// baseline (13741.449 us; speedup 1.0000x reference)
//
#include <hip/hip_runtime.h>
#include <cstddef>

#define NROWS 16385
#define NPAD  16640
#define PADT  255
#define DIM   512
#define HEADS 8
#define DH    64
#define NL    256
#define LCH   65

__device__ __forceinline__ float wsum(float v){
#pragma unroll
  for (int o = 32; o; o >>= 1) v += __shfl_xor(v, o);
  return v;
}
__device__ __forceinline__ float wmax(float v){
#pragma unroll
  for (int o = 32; o; o >>= 1) v = fmaxf(v, __shfl_xor(v, o));
  return v;
}

// ---------------- generic tiled GEMM: C = op(alpha*A@B + bias [+C]) ----------
// grid: (ceil(N/128), ceil(M/128), batch), block 256
__global__ __launch_bounds__(256) void gemm_kernel(
    const float* __restrict__ A, const float* __restrict__ B,
    const float* __restrict__ bias, float* __restrict__ C,
    int M, int N, int K, long sA, long sB, long sC,
    float alpha, int relu, int accum)
{
  if (blockIdx.z){ A += (size_t)blockIdx.z*sA; B += (size_t)blockIdx.z*sB; C += (size_t)blockIdx.z*sC; }
  __shared__ float As[8][128];
  __shared__ float Bs[8][128];
  const int t = threadIdx.x;
  const int tx = t & 15, ty = t >> 4;
  const int bm = blockIdx.y << 7, bn = blockIdx.x << 7;
  const int ar = t >> 1, ak = (t & 1) << 2;
  const int kb = t >> 5, nb = (t & 31) << 2;
  float acc[8][8];
#pragma unroll
  for (int i=0;i<8;++i)
#pragma unroll
    for (int j=0;j<8;++j) acc[i][j]=0.f;

  for (int k0 = 0; k0 < K; k0 += 8){
    __syncthreads();
    {
      int row = bm + ar;
      float4 av = make_float4(0.f,0.f,0.f,0.f);
      if (row < M) av = *(const float4*)(A + (size_t)row*K + (k0+ak));
      As[ak  ][ar]=av.x; As[ak+1][ar]=av.y; As[ak+2][ar]=av.z; As[ak+3][ar]=av.w;
    }
    {
      int col = bn + nb;
      float4 bv = make_float4(0.f,0.f,0.f,0.f);
      if (col < N) bv = *(const float4*)(B + (size_t)(k0+kb)*N + col);
      *(float4*)&Bs[kb][nb] = bv;
    }
    __syncthreads();
#pragma unroll
    for (int kk=0;kk<8;++kk){
      float4 a0 = *(const float4*)&As[kk][ty<<2];
      float4 a1 = *(const float4*)&As[kk][(ty<<2)+64];
      float4 b0 = *(const float4*)&Bs[kk][tx<<2];
      float4 b1 = *(const float4*)&Bs[kk][(tx<<2)+64];
      float ar_[8]={a0.x,a0.y,a0.z,a0.w,a1.x,a1.y,a1.z,a1.w};
      float br_[8]={b0.x,b0.y,b0.z,b0.w,b1.x,b1.y,b1.z,b1.w};
#pragma unroll
      for (int i=0;i<8;++i)
#pragma unroll
        for (int j=0;j<8;++j) acc[i][j] += ar_[i]*br_[j];
    }
  }
#pragma unroll
  for (int i=0;i<8;++i){
    int row = bm + (ty<<2) + (i&3) + ((i>>2)<<6);
    if (row >= M) continue;
#pragma unroll
    for (int j=0;j<8;++j){
      int col = bn + (tx<<2) + (j&3) + ((j>>2)<<6);
      if (col >= N) continue;
      float v = alpha*acc[i][j];
      if (bias) v += bias[col];
      if (accum) v += C[(size_t)row*N + col];
      if (relu) v = fmaxf(v, 0.f);
      C[(size_t)row*N + col] = v;
    }
  }
}

// -------- LayerNorm rows of X (16385x512) -> padded Y (16640x512, top 255 = 0)
__global__ __launch_bounds__(256) void ln_pad_kernel(
    const float* __restrict__ X, const float* __restrict__ g,
    const float* __restrict__ b, float* __restrict__ Y)
{
  int p = blockIdx.x;
  int t = threadIdx.x;
  float* yr = Y + (size_t)p*DIM;
  if (p < PADT){ yr[t] = 0.f; yr[t+256] = 0.f; return; }
  const float* xr = X + (size_t)(p-PADT)*DIM;
  float x0 = xr[t], x1 = xr[t+256];
  float s = x0 + x1, sq = x0*x0 + x1*x1;
  s = wsum(s); sq = wsum(sq);
  __shared__ float rs[4], rq[4];
  if ((t&63)==0){ rs[t>>6]=s; rq[t>>6]=sq; }
  __syncthreads();
  float S = rs[0]+rs[1]+rs[2]+rs[3];
  float SQ = rq[0]+rq[1]+rq[2]+rq[3];
  float mu = S * (1.f/DIM);
  float var = SQ * (1.f/DIM) - mu*mu;
  float r = rsqrtf(var + 1e-5f);
  yr[t]     = (x0-mu)*r*g[t]     + b[t];
  yr[t+256] = (x1-mu)*r*g[t+256] + b[t+256];
}

// -------- landmark means: QL (scaled by 1/8), KL;  grid (256, 8), block 64
__global__ void landmarks_kernel(const float* __restrict__ QKV,
                                 float* __restrict__ QL, float* __restrict__ KL)
{
  int m = blockIdx.x, h = blockIdx.y, d = threadIdx.x;
  float sq = 0.f, sk = 0.f;
  const float* base = QKV + (size_t)(m*LCH)*1536 + (h<<6) + d;
  for (int j = 0; j < LCH; ++j){
    sq += base[0];
    sk += base[512];
    base += 1536;
  }
  QL[(((h<<8)+m)<<6) + d] = sq * (0.125f/65.f);
  KL[(((h<<8)+m)<<6) + d] = sk * (1.f/65.f);
}

// -------- sim2 + softmax -> A2; grid (256, 8), block 256
__global__ __launch_bounds__(256) void sim2_kernel(
    const float* __restrict__ QL, const float* __restrict__ KL, float* __restrict__ A2)
{
  int m = blockIdx.x, h = blockIdx.y, n = threadIdx.x;
  __shared__ float ql[64];
  __shared__ float red[4];
  if (n < 64) ql[n] = QL[(((h<<8)+m)<<6) + n];
  __syncthreads();
  const float* kl = KL + (size_t)(((h<<8)+n)<<6);
  float s = 0.f;
#pragma unroll
  for (int d=0; d<64; ++d) s += ql[d]*kl[d];
  float mx = wmax(s);
  if ((n&63)==0) red[n>>6] = mx;
  __syncthreads();
  mx = fmaxf(fmaxf(red[0],red[1]), fmaxf(red[2],red[3]));
  float e = __expf(s - mx);
  float sm = wsum(e);
  __syncthreads();
  if ((n&63)==0) red[n>>6] = sm;
  __syncthreads();
  sm = red[0]+red[1]+red[2]+red[3];
  A2[((size_t)((h<<8)+m)<<8) + n] = e/sm;
}

// -------- abs row/col sums of A2 and 1/(max*max)
__global__ void colsum_kernel(const float* __restrict__ A2, float* __restrict__ CR)
{
  int r = blockIdx.x, t = threadIdx.x;          // r = h*256+m, sum over n
  float v = fabsf(A2[((size_t)r<<8) + t]);
  v = wsum(v);
  __shared__ float red[4];
  if ((t&63)==0) red[t>>6]=v;
  __syncthreads();
  if (t==0) CR[r] = red[0]+red[1]+red[2]+red[3];
}
__global__ void rowsum_kernel(const float* __restrict__ A2, float* __restrict__ CR)
{
  int r = blockIdx.x, t = threadIdx.x;          // r = h*256+n, sum over m
  int h = r >> 8, n = r & 255;
  float v = fabsf(A2[((size_t)h<<16) + (t<<8) + n]);
  v = wsum(v);
  __shared__ float red[4];
  if ((t&63)==0) red[t>>6]=v;
  __syncthreads();
  if (t==0) CR[2048 + r] = red[0]+red[1]+red[2]+red[3];
}
__global__ void maxprod_kernel(const float* __restrict__ CR, float* __restrict__ SCAL)
{
  int t = threadIdx.x;
  float mc = -3e38f, mr = -3e38f;
  for (int i=t; i<2048; i+=256){ mc = fmaxf(mc, CR[i]); mr = fmaxf(mr, CR[2048+i]); }
  mc = wmax(mc); mr = wmax(mr);
  __shared__ float rc[4], rr[4];
  if ((t&63)==0){ rc[t>>6]=mc; rr[t>>6]=mr; }
  __syncthreads();
  if (t==0){
    float a = fmaxf(fmaxf(rc[0],rc[1]),fmaxf(rc[2],rc[3]));
    float b = fmaxf(fmaxf(rr[0],rr[1]),fmaxf(rr[2],rr[3]));
    SCAL[0] = 1.f/(a*b);
  }
}
// Z[h][n][m] = A2[h][m][n] * SCAL[0]; grid 2048, block 256
__global__ void tscale_kernel(const float* __restrict__ A2, const float* __restrict__ SCAL,
                              float* __restrict__ Z)
{
  int idx = blockIdx.x*256 + threadIdx.x;
  int h = idx >> 16, rem = idx & 65535, m = rem >> 8, n = rem & 255;
  Z[((size_t)h<<16) + (n<<8) + m] = A2[idx] * SCAL[0];
}
// out = alpha*I - in; grid 2048, block 256
__global__ void aim_kernel(const float* __restrict__ in, float* __restrict__ out, float alpha)
{
  int idx = blockIdx.x*256 + threadIdx.x;
  int rem = idx & 65535;
  float d = ((rem>>8) == (rem&255)) ? alpha : 0.f;
  out[idx] = d - in[idx];
}

// -------- fused sim3 softmax @ V (streamed): TMP[h,m,:]; grid (256,8), block 256
__global__ __launch_bounds__(256) void lattn_kernel(
    const float* __restrict__ QKV, const float* __restrict__ QL, float* __restrict__ TMP)
{
  int m = blockIdx.x, h = blockIdx.y;
  int t = threadIdx.x, lane = t & 63, wv = t >> 6;
  float ql = QL[(((h<<8)+m)<<6) + lane];
  float M = -3e38f, S = 0.f, acc = 0.f;
  const float* base = QKV + 512 + (h<<6) + lane;
  for (int j = wv; j < NPAD; j += 4){
    const float* p = base + (size_t)j*1536;
    float kk = p[0];
    float vv = p[512];
    float s = ql * kk;
#pragma unroll
    for (int o=32;o;o>>=1) s += __shfl_xor(s, o);
    float Mn = fmaxf(M, s);
    float sc = __expf(M - Mn);
    float w  = __expf(s - Mn);
    S   = S*sc + w;
    acc = acc*sc + w*vv;
    M = Mn;
  }
  __shared__ float sM[4], sS[4], sA[4][64];
  sA[wv][lane] = acc;
  if (lane==0){ sM[wv]=M; sS[wv]=S; }
  __syncthreads();
  if (t < 64){
    float Mg = fmaxf(fmaxf(sM[0],sM[1]), fmaxf(sM[2],sM[3]));
    float Sg = 0.f, Ag = 0.f;
#pragma unroll
    for (int w2=0; w2<4; ++w2){
      float f = __expf(sM[w2]-Mg);
      Sg += sS[w2]*f;
      Ag += sA[w2][t]*f;
    }
    TMP[(((h<<8)+m)<<6) + t] = Ag/Sg;
  }
}

// -------- fused sim1 softmax @ BM -> ATT rows 255..; grid 16385, block 256
__global__ __launch_bounds__(256) void attn_out_kernel(
    const float* __restrict__ QKV, const float* __restrict__ KL,
    const float* __restrict__ BM, float* __restrict__ ATT)
{
  int i = PADT + blockIdx.x;
  int t = threadIdx.x;
  __shared__ float qv[64];
  __shared__ float red[256];
  __shared__ float wred[4];
  for (int h = 0; h < HEADS; ++h){
    __syncthreads();
    if (t < 64) qv[t] = QKV[(size_t)i*1536 + (h<<6) + t] * 0.125f;
    __syncthreads();
    const float* kl = KL + (size_t)(((h<<8)+t)<<6);
    float s = 0.f;
#pragma unroll
    for (int d=0; d<64; ++d) s += qv[d]*kl[d];
    float mx = wmax(s);
    if ((t&63)==0) wred[t>>6] = mx;
    __syncthreads();
    mx = fmaxf(fmaxf(wred[0],wred[1]), fmaxf(wred[2],wred[3]));
    float e = __expf(s - mx);
    float sm = wsum(e);
    __syncthreads();
    if ((t&63)==0) wred[t>>6] = sm;
    __syncthreads();
    sm = wred[0]+wred[1]+wred[2]+wred[3];
    red[t] = e / sm;
    __syncthreads();
    int d = t & 63, mq = t >> 6;
    const float* bp = BM + (size_t)(((h<<8) + (mq<<6))<<6) + d;
    float acc = 0.f;
#pragma unroll 8
    for (int mm=0; mm<64; ++mm) acc += red[(mq<<6)+mm] * bp[mm<<6];
    __syncthreads();
    red[t] = acc;
    __syncthreads();
    if (t < 64){
      float o = red[t] + red[64+t] + red[128+t] + red[192+t];
      ATT[(size_t)i*DIM + (h<<6) + t] = o;
    }
    __syncthreads();
  }
}

// -------- depthwise 33-tap conv residual: ATT += conv(v); grid (16385,2), block 256
__global__ void convres_kernel(const float* __restrict__ QKV, const float* __restrict__ rw,
                               float* __restrict__ ATT)
{
  int c = blockIdx.y*256 + threadIdx.x;
  int i = PADT + blockIdx.x;
  int h = c >> 6;
  const float* w = rw + h*33;
  const float* v = QKV + 1024 + c;
  float acc = 0.f;
#pragma unroll
  for (int k=0; k<33; ++k){
    int j = i - 16 + k;
    if (j < NPAD) acc += w[k] * v[(size_t)j*1536];
  }
  ATT[(size_t)i*DIM + c] += acc;
}

// -------- PPEG: X(16385x512) -> X2 rows 1..; grid (2,16384), block 256
__global__ void ppeg_kernel(const float* __restrict__ X,
                            const float* __restrict__ w7, const float* __restrict__ b7,
                            const float* __restrict__ w5, const float* __restrict__ b5,
                            const float* __restrict__ w3, const float* __restrict__ b3,
                            float* __restrict__ X2)
{
  int c = blockIdx.x*256 + threadIdx.x;
  int p = blockIdx.y;
  int y = p >> 7, x = p & 127;
  const float* base = X + DIM + c;   // feat[p][c]
  float acc = base[(size_t)p*DIM] + b7[c] + b5[c] + b3[c];
  const float* W7 = w7 + c*49;
#pragma unroll
  for (int ky=0; ky<7; ++ky){ int yy = y+ky-3; if ((unsigned)yy > 127u) continue;
#pragma unroll
    for (int kx=0; kx<7; ++kx){ int xx = x+kx-3; if ((unsigned)xx > 127u) continue;
      acc += W7[ky*7+kx] * base[(size_t)(yy*128+xx)*DIM]; } }
  const float* W5 = w5 + c*25;
#pragma unroll
  for (int ky=0; ky<5; ++ky){ int yy = y+ky-2; if ((unsigned)yy > 127u) continue;
#pragma unroll
    for (int kx=0; kx<5; ++kx){ int xx = x+kx-2; if ((unsigned)xx > 127u) continue;
      acc += W5[ky*5+kx] * base[(size_t)(yy*128+xx)*DIM]; } }
  const float* W3 = w3 + c*9;
#pragma unroll
  for (int ky=0; ky<3; ++ky){ int yy = y+ky-1; if ((unsigned)yy > 127u) continue;
#pragma unroll
    for (int kx=0; kx<3; ++kx){ int xx = x+kx-1; if ((unsigned)xx > 127u) continue;
      acc += W3[ky*3+kx] * base[(size_t)(yy*128+xx)*DIM]; } }
  X2[(size_t)(1+p)*DIM + c] = acc;
}

__global__ void copy_row_kernel(const float* __restrict__ src, float* __restrict__ dst)
{
  dst[threadIdx.x] = src[threadIdx.x];
}

// -------- final: LN(row0) @ fc2 + b; 1 block 256
__global__ void final_kernel(const float* __restrict__ X, const float* __restrict__ g,
                             const float* __restrict__ b, const float* __restrict__ fw,
                             const float* __restrict__ fb, float* __restrict__ out)
{
  int t = threadIdx.x;
  float x0 = X[t], x1 = X[t+256];
  float s = x0 + x1, sq = x0*x0 + x1*x1;
  s = wsum(s); sq = wsum(sq);
  __shared__ float rs[4], rq[4];
  if ((t&63)==0){ rs[t>>6]=s; rq[t>>6]=sq; }
  __syncthreads();
  float S = rs[0]+rs[1]+rs[2]+rs[3];
  float SQ = rq[0]+rq[1]+rq[2]+rq[3];
  float mu = S*(1.f/DIM);
  float var = SQ*(1.f/DIM) - mu*mu;
  float r = rsqrtf(var + 1e-5f);
  float n0 = (x0-mu)*r*g[t]     + b[t];
  float n1 = (x1-mu)*r*g[t+256] + b[t+256];
  float p0 = n0*fw[t*2]   + n1*fw[(t+256)*2];
  float p1 = n0*fw[t*2+1] + n1*fw[(t+256)*2+1];
  p0 = wsum(p0); p1 = wsum(p1);
  __shared__ float r0[4], r1[4];
  if ((t&63)==0){ r0[t>>6]=p0; r1[t>>6]=p1; }
  __syncthreads();
  if (t==0){
    out[0] = r0[0]+r0[1]+r0[2]+r0[3] + fb[0];
    out[1] = r1[0]+r1[1]+r1[2]+r1[3] + fb[1];
  }
}

// ======================= host orchestration =======================
struct Bufs {
  float *Y, *QKV, *QL, *KL, *A2, *Z0, *Z1, *XZ, *W, *W2, *CR, *SCAL, *TMP, *BM;
};

static void attention_layer(float* X, const float* ln_g, const float* ln_b,
                            const float* qkv_w, const float* out_w, const float* out_b,
                            const float* res_w, Bufs& bf, hipStream_t stream)
{
  ln_pad_kernel<<<NPAD, 256, 0, stream>>>(X, ln_g, ln_b, bf.Y);
  // QKV = Y @ qkv_w  (16640 x 512 @ 512 x 1536)
  gemm_kernel<<<dim3(12,130,1),256,0,stream>>>(bf.Y, qkv_w, nullptr, bf.QKV,
      NPAD, 1536, DIM, 0,0,0, 1.f, 0, 0);
  landmarks_kernel<<<dim3(NL,HEADS),64,0,stream>>>(bf.QKV, bf.QL, bf.KL);
  sim2_kernel<<<dim3(NL,HEADS),256,0,stream>>>(bf.QL, bf.KL, bf.A2);
  colsum_kernel<<<2048,256,0,stream>>>(bf.A2, bf.CR);
  rowsum_kernel<<<2048,256,0,stream>>>(bf.A2, bf.CR);
  maxprod_kernel<<<1,256,0,stream>>>(bf.CR, bf.SCAL);
  tscale_kernel<<<2048,256,0,stream>>>(bf.A2, bf.SCAL, bf.Z0);
  float* Za = bf.Z0; float* Zb = bf.Z1;
  const long SB = 65536;
  for (int it = 0; it < 6; ++it){
    gemm_kernel<<<dim3(2,2,8),256,0,stream>>>(bf.A2, Za, nullptr, bf.XZ, 256,256,256, SB,SB,SB, 1.f,0,0);
    aim_kernel<<<2048,256,0,stream>>>(bf.XZ, bf.W, 7.f);
    gemm_kernel<<<dim3(2,2,8),256,0,stream>>>(bf.XZ, bf.W, nullptr, bf.W2, 256,256,256, SB,SB,SB, 1.f,0,0);
    aim_kernel<<<2048,256,0,stream>>>(bf.W2, bf.W, 15.f);
    gemm_kernel<<<dim3(2,2,8),256,0,stream>>>(bf.XZ, bf.W, nullptr, bf.W2, 256,256,256, SB,SB,SB, 1.f,0,0);
    aim_kernel<<<2048,256,0,stream>>>(bf.W2, bf.W, 13.f);
    gemm_kernel<<<dim3(2,2,8),256,0,stream>>>(Za, bf.W, nullptr, Zb, 256,256,256, SB,SB,SB, 0.25f,0,0);
    float* tp = Za; Za = Zb; Zb = tp;
  }
  lattn_kernel<<<dim3(NL,HEADS),256,0,stream>>>(bf.QKV, bf.QL, bf.TMP);
  // BM = Zinv @ TMP  (batched 256x256 @ 256x64)
  gemm_kernel<<<dim3(1,2,8),256,0,stream>>>(Za, bf.TMP, nullptr, bf.BM, 256,64,256, SB, 16384L, 16384L, 1.f,0,0);
  float* ATT = bf.Y;   // reuse Y region
  attn_out_kernel<<<NROWS,256,0,stream>>>(bf.QKV, bf.KL, bf.BM, ATT);
  convres_kernel<<<dim3(NROWS,2),256,0,stream>>>(bf.QKV, res_w, ATT);
  // X += ATT[255:] @ out_w + out_b
  gemm_kernel<<<dim3(4,129,1),256,0,stream>>>(ATT + (size_t)PADT*DIM, out_w, out_b, X,
      NROWS, DIM, DIM, 0,0,0, 1.f, 0, 1);
}

extern "C" void kernel_launch(void* const* d_in, const int* in_sizes, int n_in,
                              void* d_out, int out_size, void* d_ws, size_t ws_size,
                              hipStream_t stream)
{
  (void)in_sizes; (void)n_in; (void)out_size; (void)ws_size;
  const float* h       = (const float*)d_in[0];
  const float* fc1_w   = (const float*)d_in[1];
  const float* fc1_b   = (const float*)d_in[2];
  const float* cls     = (const float*)d_in[3];
  const float* l1_ln_g = (const float*)d_in[4];
  const float* l1_ln_b = (const float*)d_in[5];
  const float* l1_qkv_w= (const float*)d_in[6];
  const float* l1_out_w= (const float*)d_in[7];
  const float* l1_out_b= (const float*)d_in[8];
  const float* l1_res_w= (const float*)d_in[9];
  const float* conv7_w = (const float*)d_in[10];
  const float* conv7_b = (const float*)d_in[11];
  const float* conv5_w = (const float*)d_in[12];
  const float* conv5_b = (const float*)d_in[13];
  const float* conv3_w = (const float*)d_in[14];
  const float* conv3_b = (const float*)d_in[15];
  const float* l2_ln_g = (const float*)d_in[16];
  const float* l2_ln_b = (const float*)d_in[17];
  const float* l2_qkv_w= (const float*)d_in[18];
  const float* l2_out_w= (const float*)d_in[19];
  const float* l2_out_b= (const float*)d_in[20];
  const float* l2_res_w= (const float*)d_in[21];
  const float* norm_g  = (const float*)d_in[22];
  const float* norm_b  = (const float*)d_in[23];
  const float* fc2_w   = (const float*)d_in[24];
  const float* fc2_b   = (const float*)d_in[25];

  float* ws = (float*)d_ws;
  float* X   = ws;                 ws += (size_t)NROWS*DIM;
  float* X2  = ws;                 ws += (size_t)NROWS*DIM;
  Bufs bf;
  bf.Y   = ws;                     ws += (size_t)NPAD*DIM;
  bf.QKV = ws;                     ws += (size_t)NPAD*1536;
  bf.QL  = ws;                     ws += HEADS*NL*DH;
  bf.KL  = ws;                     ws += HEADS*NL*DH;
  bf.A2  = ws;                     ws += HEADS*NL*NL;
  bf.Z0  = ws;                     ws += HEADS*NL*NL;
  bf.Z1  = ws;                     ws += HEADS*NL*NL;
  bf.XZ  = ws;                     ws += HEADS*NL*NL;
  bf.W   = ws;                     ws += HEADS*NL*NL;
  bf.W2  = ws;                     ws += HEADS*NL*NL;
  bf.CR  = ws;                     ws += 4096;
  bf.SCAL= ws;                     ws += 8;
  bf.TMP = ws;                     ws += HEADS*NL*DH;
  bf.BM  = ws;                     ws += HEADS*NL*DH;

  // x = relu(h @ fc1_w + fc1_b); X rows 1..16384; X[0] = cls
  gemm_kernel<<<dim3(4,128,1),256,0,stream>>>(h, fc1_w, fc1_b, X + DIM,
      16384, DIM, 2048, 0,0,0, 1.f, 1, 0);
  copy_row_kernel<<<1,512,0,stream>>>(cls, X);

  attention_layer(X, l1_ln_g, l1_ln_b, l1_qkv_w, l1_out_w, l1_out_b, l1_res_w, bf, stream);

  ppeg_kernel<<<dim3(2,16384),256,0,stream>>>(X, conv7_w, conv7_b, conv5_w, conv5_b,
                                              conv3_w, conv3_b, X2);
  copy_row_kernel<<<1,512,0,stream>>>(X, X2);

  attention_layer(X2, l2_ln_g, l2_ln_b, l2_qkv_w, l2_out_w, l2_out_b, l2_res_w, bf, stream);

  final_kernel<<<1,256,0,stream>>>(X2, norm_g, norm_b, fc2_w, fc2_b, (float*)d_out);
}